// Round 6
// baseline (1231.694 us; speedup 1.0000x reference)
//
#include <hip/hip_runtime.h>
#include <hip/hip_bf16.h>

#define BATCH 4096
#define TSTEPS 80
#define VOCAB 10000
#define EDIM 100
#define UDIM 1024

// LDS: B weights 4 j x 36 s x 64 lanes x 16 B = 147456 B
//      + 8 waves x 640-half epilogue scratch = 10240 B -> 157696 B static
#define B_HALFS 73728

// s_getreg imm: hwreg(HW_REG_XCC_ID=20, offset=0, size=32) = 20 | (31<<11)
#define HWREG_XCC_ID 63508

typedef _Float16 half8 __attribute__((ext_vector_type(8)));
typedef float float4v __attribute__((ext_vector_type(4)));

// Frag-major layout: chunk(blk, kblk, lane) = 16 B holding
// row = blk*16 + (lane&15), k = kblk*32 + (lane>>4)*8 .. +8.
// h:  [mblk 256][kblk 32][lane]   Wf: [nblk 64][kblk 32][lane]
// xe: [t][mblk 256][kblk 4][lane] Wxf:[nblk 64][kblk 4][lane]

__device__ __forceinline__ void load_lds16(const void* g, void* l) {
    __builtin_amdgcn_global_load_lds(
        (const __attribute__((address_space(1))) unsigned int*)g,
        (__attribute__((address_space(3))) unsigned int*)l,
        16, 0, 0);
}

__device__ __forceinline__ float tanh_fast(float x) {
    return 1.0f - 2.0f / (__expf(2.0f * x) + 1.0f);
}

__global__ __launch_bounds__(256) void convert_wh_frag(const float* __restrict__ Wh,
                                                       _Float16* __restrict__ Wf) {
    int cid = blockIdx.x * 256 + threadIdx.x;
    int lane = cid & 63, kblk = (cid >> 6) & 31, nblk = cid >> 11;
    int n = nblk * 16 + (lane & 15);
    int kb = kblk * 32 + (lane >> 4) * 8;
    half8 v;
    #pragma unroll
    for (int e = 0; e < 8; ++e) v[e] = (_Float16)Wh[(kb + e) * UDIM + n];
    *((half8*)Wf + cid) = v;
}

__global__ __launch_bounds__(256) void convert_wx_frag(const float* __restrict__ Wx,
                                                       _Float16* __restrict__ Wxf) {
    int cid = blockIdx.x * 256 + threadIdx.x;
    int lane = cid & 63, kblk = (cid >> 6) & 3, nblk = cid >> 8;
    int n = nblk * 16 + (lane & 15);
    int kb = kblk * 32 + (lane >> 4) * 8;
    half8 v;
    #pragma unroll
    for (int e = 0; e < 8; ++e)
        v[e] = (kb + e < EDIM) ? (_Float16)Wx[(kb + e) * UDIM + n] : (_Float16)0.0f;
    *((half8*)Wxf + cid) = v;
}

// 2 independent token->emb chains per thread (gather-latency-bound kernel)
__global__ __launch_bounds__(256) void embed_gather_frag(
        const int* __restrict__ inputs, const float* __restrict__ emb,
        _Float16* __restrict__ xe) {
    const int c = blockIdx.x * 256 + threadIdx.x;
    int cid[2] = { c, c + 2621440 };
    const float* src[2];
    int kb[2];
    #pragma unroll
    for (int u = 0; u < 2; ++u) {
        int lane = cid[u] & 63, kblk = (cid[u] >> 6) & 3;
        int mblk = (cid[u] >> 8) & 255, t = cid[u] >> 16;
        int m = mblk * 16 + (lane & 15);
        kb[u] = kblk * 32 + (lane >> 4) * 8;
        int tok = inputs[m * TSTEPS + t];
        src[u] = emb + (size_t)tok * EDIM;
    }
    #pragma unroll
    for (int u = 0; u < 2; ++u) {
        half8 v;
        #pragma unroll
        for (int e = 0; e < 8; ++e)
            v[e] = (kb[u] + e < EDIM) ? (_Float16)src[u][kb[u] + e] : (_Float16)0.0f;
        *((half8*)xe + cid[u]) = v;
    }
}

// Persistent kernel, 256 blocks x 512 threads (2 waves/SIMD; 157.7 KB LDS
// keeps 1 block/CU). Tile 256(M) x 64(N), waves split M only (32M x 64N).
// B pinned in LDS all 80 steps; B dist-2, A dist-4 (r0 schedule); rotated
// visit order + own-chunk registers (r4, best known: 863 us).
// NEW (this round): TWO INDEPENDENT HALF-BLOCK CHAINS, ANTI-PHASED.
// Waves 0-3 own rows 0..127 (H0), waves 4-7 own rows 128..255 (H1).
// Block (mt,nt) reads only its own mt rows, and H0 rows are written only by
// the grid's H0 halves -> the chains share NO data, only hardware. Fast
// mode therefore drops __syncthreads entirely: each half syncs via a
// 4-wave LDS soft-barrier (s_waitcnt(0) + ds_add + uniform spin), posts a
// per-(mt,half) flag, then 16-lane-spins on its own 16 flags. H1 is seeded
// ~13k cyc (half a step) behind H0, so on every SIMD one wave computes
// while its partner is in barrier/epilogue/latency -- phase-diverse waves
// at UNCHANGED per-CU L2/LDS/MFMA traffic (R5 showed traffic-doubling
// occupancy backfires; this gets the overlap without the traffic).
// WAR skew bound within each chain is the same flag-per-step argument as
// the previous validated barrier. Fallback (!fast) keeps the original
// full-block fenced barrier, unchanged.
__global__ __launch_bounds__(512, 2) void rnn_persist(
        _Float16* __restrict__ hA, _Float16* __restrict__ hB,
        const _Float16* __restrict__ xe,
        const _Float16* __restrict__ Wf, const _Float16* __restrict__ Wxf,
        const float* __restrict__ bias,
        unsigned* vote, unsigned* barg, unsigned* bar, unsigned* fbar)
{
    __shared__ __align__(16) _Float16 smem[B_HALFS + 8 * 640];  // 157696 B
    __shared__ unsigned sFast;
    __shared__ unsigned scnt[2];                  // per-half soft-barrier counters

    const int tid  = threadIdx.x;
    const int lane = tid & 63, wave = tid >> 6;
    const int bid  = blockIdx.x;
    const int mt = bid & 15, nt = bid >> 4;
    const int lrow = lane & 15, lq = lane >> 4;
    const int half = wave >> 2;                   // H0: waves 0-3, H1: waves 4-7

    if (tid < 2) scnt[tid] = 0u;

    // ---- XCD-locality vote + one global barrier (atomics only) ----
    if (tid == 0) {
        unsigned xcd = ((unsigned)__builtin_amdgcn_s_getreg(HWREG_XCC_ID)) & 7u;
        __hip_atomic_fetch_or(&vote[mt], 1u << xcd, __ATOMIC_RELAXED,
                              __HIP_MEMORY_SCOPE_AGENT);
        __builtin_amdgcn_s_waitcnt(0);
        __hip_atomic_fetch_add(barg, 1u, __ATOMIC_RELAXED, __HIP_MEMORY_SCOPE_AGENT);
        while (__hip_atomic_load(barg, __ATOMIC_RELAXED,
                                 __HIP_MEMORY_SCOPE_AGENT) < 256u)
            __builtin_amdgcn_s_sleep(1);
        unsigned allv = 0u, own = 0u;
        for (int g = 0; g < 16; ++g) {
            unsigned v = __hip_atomic_load(&vote[g], __ATOMIC_RELAXED,
                                           __HIP_MEMORY_SCOPE_AGENT);
            allv |= v;
            if (g == mt) own = v;
        }
        const bool single = own != 0u && (own & (own - 1u)) == 0u;
        sFast = (single && __popc(allv) == 8) ? 1u : 0u;
    }
    __syncthreads();
    const bool fast = sFast != 0u;

    // ---- Load B slice into LDS once: [j(4)][s(36)][lane][8]; waves 0-3 ----
    if (wave < 4) {
        const half8* wx8 = (const half8*)Wxf;
        const half8* wh8 = (const half8*)Wf;
        #pragma unroll 1
        for (int s = 0; s < 36; ++s) {
            const half8* src = (s < 4)
                ? wx8 + ((size_t)(nt * 4 + wave) * 4 + s) * 64 + lane
                : wh8 + ((size_t)(nt * 4 + wave) * 32 + (s - 4)) * 64 + lane;
            load_lds16(src, smem + ((wave * 36 + s) * 64 + lane) * 8);
        }
    }
    __syncthreads();

    // ---- Anti-phase seed: H1 lags ~half a step (13k cyc). One-time cost.
    if (fast && half == 1) {
        #pragma unroll 1
        for (int i = 0; i < 30; ++i) __builtin_amdgcn_s_sleep(7);
    }

    _Float16* tb = smem + B_HALFS + wave * 640;   // epilogue scratch, wave-private

    float bj[4];
    #pragma unroll
    for (int j = 0; j < 4; ++j) bj[j] = bias[nt * 64 + j * 16 + lrow];

    int mblk[2];                                  // wave tile: 32 M rows
    #pragma unroll
    for (int i = 0; i < 2; ++i) mblk[i] = mt * 16 + wave * 2 + i;

    unsigned* mybar = bar + mt * 32;              // fallback single counter
    unsigned* fb = fbar + (size_t)(mt * 2 + half) * 64;  // my half's 16 flags (16B stride)

    const int cb = nt * 2;                        // rotated chunk base

#define LDB(bf, s) { _Pragma("unroll") \
    for (int j = 0; j < 4; ++j) \
        bf[j] = *(const half8*)&smem[(((j) * 36 + (s)) * 64 + lane) * 8]; }
#define LDBR(bf, v) { const int s_ = 4 + ((cb + (v)) & 31); _Pragma("unroll") \
    for (int j = 0; j < 4; ++j) \
        bf[j] = *(const half8*)&smem[((j * 36 + s_) * 64 + lane) * 8]; }
#define FMAB(A, B) { _Pragma("unroll") \
    for (int i = 0; i < 2; ++i) { _Pragma("unroll") \
        for (int j = 0; j < 4; ++j) \
            acc[i][j] = __builtin_amdgcn_mfma_f32_16x16x32_f16(A[i], B[j], acc[i][j], 0, 0, 0); } }
#define LDHR(A, v) { const int c_ = (cb + (v)) & 31; _Pragma("unroll") \
    for (int i = 0; i < 2; ++i) A[i] = pah[i][c_ * 64]; }
#define ZACC { _Pragma("unroll") \
    for (int i = 0; i < 2; ++i) { _Pragma("unroll") \
        for (int j = 0; j < 4; ++j) { acc[i][j][0]=0.f; acc[i][j][1]=0.f; acc[i][j][2]=0.f; acc[i][j][3]=0.f; } } }

    float4v acc[2][4];
    half8 a0[2], a1[2], a2[2], a3[2], b0[4], b1[4];
    half8 own0[2], own1[2];                       // own chunks (visits 0,1); h(0)=0
    #pragma unroll
    for (int e = 0; e < 8; ++e) {
        own0[0][e] = (_Float16)0.0f; own0[1][e] = (_Float16)0.0f;
        own1[0][e] = (_Float16)0.0f; own1[1][e] = (_Float16)0.0f;
    }

    // x-segment for a step: acc += xe_tn @ Wx  (B slices 0..3)
    auto xfma = [&](int tn) {
        const half8* xe8 = (const half8*)xe + (size_t)tn * 65536;
        #pragma unroll
        for (int i = 0; i < 2; ++i) {
            const half8* px = xe8 + (size_t)mblk[i] * 4 * 64 + lane;
            a0[i] = px[0]; a1[i] = px[64]; a2[i] = px[128]; a3[i] = px[192];
        }
        LDB(b0, 0); LDB(b1, 1);
        FMAB(a0, b0); LDB(b0, 2);
        FMAB(a1, b1); LDB(b1, 3);
        FMAB(a2, b0);
        FMAB(a3, b1);
    };

    ZACC;
    xfma(0);

    #pragma unroll 1
    for (int t = 0; t < TSTEPS; ++t) {
        const _Float16* hi = (t & 1) ? hB : hA;
        _Float16*       ho = (t & 1) ? hA : hB;

        const half8* pah[2];
        #pragma unroll
        for (int i = 0; i < 2; ++i)
            pah[i] = (const half8*)hi + (size_t)mblk[i] * 32 * 64 + lane;

        // ---- h-loop: 32 visits, rotated order chunk=(2nt+v)&31.
        //      Visits 0,1 = own chunks from registers (no load, no latency).
        //      A dist-4 (a2,a3 then loop-carried), B dist-2 (r0 schedule).
        #pragma unroll
        for (int i = 0; i < 2; ++i) { a0[i] = own0[i]; a1[i] = own1[i]; }
        LDHR(a2, 2); LDHR(a3, 3);
        LDBR(b0, 0); LDBR(b1, 1);
        #pragma unroll 1
        for (int v = 0; v < 28; v += 4) {
            FMAB(a0, b0); LDBR(b0, v + 2); LDHR(a0, v + 4);
            FMAB(a1, b1); LDBR(b1, v + 3); LDHR(a1, v + 5);
            FMAB(a2, b0); LDBR(b0, v + 4); LDHR(a2, v + 6);
            FMAB(a3, b1); LDBR(b1, v + 5); LDHR(a3, v + 7);
        }
        // tail: visits 28..31
        FMAB(a0, b0); LDBR(b0, 30);
        FMAB(a1, b1); LDBR(b1, 31);
        FMAB(a2, b0);
        FMAB(a3, b1);

        // ---- Epilogue: tanh + C-layout -> A-layout (wave-private LDS) ----
        #pragma unroll
        for (int i = 0; i < 2; ++i) {
            #pragma unroll
            for (int jp = 0; jp < 2; ++jp) {
                #pragma unroll
                for (int jj = 0; jj < 2; ++jj) {
                    const int j = jp * 2 + jj;
                    #pragma unroll
                    for (int r = 0; r < 4; ++r)
                        tb[(lq * 4 + r) * 40 + jj * 16 + lrow] =
                            (_Float16)tanh_fast(acc[i][j][r] + bj[j]);
                }
                // same-wave LDS RAW -> lgkmcnt only, no barrier
                half8 v = *(const half8*)&tb[lrow * 40 + lq * 8];
                if (jp == 0) own0[i] = v; else own1[i] = v;   // keep own chunks
                *((half8*)ho + (size_t)(mblk[i] * 32 + nt * 2 + jp) * 64 + lane) = v;
            }
        }

        // ---- x-segment of step t+1 (independent of h_{t+1}) BEFORE sync ----
        if (t < TSTEPS - 1) {
            ZACC;
            xfma(t + 1);
            if (fast) {
                // -- per-half sync, no __syncthreads: --
                // 1) drain own stores, arrive at 4-wave LDS soft barrier
                __builtin_amdgcn_s_waitcnt(0);
                if (lane == 0)
                    __hip_atomic_fetch_add(&scnt[half], 1u, __ATOMIC_RELAXED,
                                           __HIP_MEMORY_SCOPE_WORKGROUP);
                while (__hip_atomic_load(&scnt[half], __ATOMIC_RELAXED,
                                         __HIP_MEMORY_SCOPE_WORKGROUP)
                       < 4u * (unsigned)(t + 1))
                    __builtin_amdgcn_s_sleep(1);
                // 2) all 4 waves' h stores drained -> post half flag
                if ((wave & 3) == 0 && lane == 0)
                    __hip_atomic_store(fb + nt * 4, (unsigned)(t + 1),
                                       __ATOMIC_RELAXED, __HIP_MEMORY_SCOPE_AGENT);
                // 3) wait for all 16 blocks' same-half flags
                if (lane < 16) {
                    while (__hip_atomic_load(fb + lane * 4, __ATOMIC_RELAXED,
                                             __HIP_MEMORY_SCOPE_AGENT)
                           < (unsigned)(t + 1))
                        __builtin_amdgcn_s_sleep(1);
                }
            } else {
                __syncthreads();    // drains all waves' h stores to L2
                if (tid == 0) {
                    __builtin_amdgcn_fence(__ATOMIC_RELEASE, "agent");
                    __hip_atomic_fetch_add(mybar, 1u, __ATOMIC_RELAXED,
                                           __HIP_MEMORY_SCOPE_AGENT);
                    const unsigned target = 16u * (unsigned)(t + 1);
                    while (__hip_atomic_load(mybar, __ATOMIC_RELAXED,
                                             __HIP_MEMORY_SCOPE_AGENT) < target)
                        __builtin_amdgcn_s_sleep(1);
                    __builtin_amdgcn_fence(__ATOMIC_ACQUIRE, "agent");
                }
                __syncthreads();
            }
        }
    }
#undef LDB
#undef LDBR
#undef FMAB
#undef LDHR
#undef ZACC
}

// out[b] = h[b,:].Wo + bo, h frag-major
__global__ __launch_bounds__(256) void out_proj(const _Float16* __restrict__ h,
                                                const float* __restrict__ Wo,
                                                const float* __restrict__ bo,
                                                float* __restrict__ out) {
    const int lane = threadIdx.x & 63;
    const int wave = threadIdx.x >> 6;
    const int row = blockIdx.x * 4 + wave;
    const int mblk = row >> 4, lb = row & 15;
    const half8* hf = (const half8*)h;
    float s = 0.0f;
    #pragma unroll
    for (int c = 0; c < 2; ++c) {
        const int kblk = lane >> 1;
        const int q = (lane & 1) * 2 + c;
        half8 v = hf[(size_t)(mblk * 32 + kblk) * 64 + lb + q * 16];
        const int k0 = kblk * 32 + q * 8;
        #pragma unroll
        for (int e = 0; e < 8; ++e) s += (float)v[e] * Wo[k0 + e];
    }
    #pragma unroll
    for (int off = 32; off > 0; off >>= 1) s += __shfl_down(s, off, 64);
    if (lane == 0) out[row] = s + bo[0];
}

extern "C" void kernel_launch(void* const* d_in, const int* in_sizes, int n_in,
                              void* d_out, int out_size, void* d_ws, size_t ws_size,
                              hipStream_t stream) {
    const int*   inputs = (const int*)  d_in[0];
    const float* emb    = (const float*)d_in[1];
    const float* Wx     = (const float*)d_in[2];
    const float* Wh     = (const float*)d_in[3];
    const float* b      = (const float*)d_in[4];
    const float* Wo     = (const float*)d_in[5];
    const float* bo     = (const float*)d_in[6];
    float* out = (float*)d_out;

    char* ws = (char*)d_ws;
    _Float16* Wf   = (_Float16*)ws;                          // 2 MB
    _Float16* Wxf  = (_Float16*)(ws + (2u  << 20));          // 256 KB
    _Float16* hA   = (_Float16*)(ws + (3u  << 20));          // 8 MB
    _Float16* hB   = (_Float16*)(ws + (11u << 20));          // 8 MB
    _Float16* xe   = (_Float16*)(ws + (19u << 20));          // 84 MB
    unsigned* vote = (unsigned*)(ws + (103u << 20));         // 16 u32
    unsigned* barg = vote + 16;                              // 1 u32
    unsigned* bar  = vote + 256;                             // 16 x 32-u32 (fallback)
    unsigned* fbar = vote + 1024;                            // 16mt x 2half x 16 x 4-u32 flags

    convert_wh_frag<<<dim3(512),     dim3(256), 0, stream>>>(Wh, Wf);
    convert_wx_frag<<<dim3(64),      dim3(256), 0, stream>>>(Wx, Wxf);
    embed_gather_frag<<<dim3(10240), dim3(256), 0, stream>>>(inputs, emb, xe);
    hipMemsetAsync(hA, 0, (size_t)BATCH * UDIM * sizeof(_Float16), stream);
    hipMemsetAsync(vote, 0, 16384, stream);

    rnn_persist<<<dim3(256), dim3(512), 0, stream>>>(hA, hB, xe, Wf, Wxf, b,
                                                     vote, barg, bar, fbar);

    // T=80 even -> final h in hA
    out_proj<<<dim3(1024), dim3(256), 0, stream>>>(hA, Wo, bo, out);
}

// Round 7
// 917.631 us; speedup vs baseline: 1.3423x; 1.3423x over previous
//
#include <hip/hip_runtime.h>
#include <hip/hip_bf16.h>

#define BATCH 4096
#define TSTEPS 80
#define VOCAB 10000
#define EDIM 100
#define UDIM 1024

// LDS: B weights 4 j x 36 s x 64 lanes x 16 B = 147456 B
//      + 8 waves x 640-half epilogue scratch = 10240 B -> 157696 B static
#define B_HALFS 73728

// s_getreg imm: hwreg(HW_REG_XCC_ID=20, offset=0, size=32) = 20 | (31<<11)
#define HWREG_XCC_ID 63508

typedef _Float16 half8 __attribute__((ext_vector_type(8)));
typedef float float4v __attribute__((ext_vector_type(4)));

// Frag-major layout: chunk(blk, kblk, lane) = 16 B holding
// row = blk*16 + (lane&15), k = kblk*32 + (lane>>4)*8 .. +8.
// h:  [mblk 256][kblk 32][lane]   Wf: [nblk 64][kblk 32][lane]
// xe: [t][mblk 256][kblk 4][lane] Wxf:[nblk 64][kblk 4][lane]

__device__ __forceinline__ void load_lds16(const void* g, void* l) {
    __builtin_amdgcn_global_load_lds(
        (const __attribute__((address_space(1))) unsigned int*)g,
        (__attribute__((address_space(3))) unsigned int*)l,
        16, 0, 0);
}

__device__ __forceinline__ float tanh_fast(float x) {
    return 1.0f - 2.0f / (__expf(2.0f * x) + 1.0f);
}

// ---------------------------------------------------------------------------
// PREP: one kernel replaces {convert_wh, convert_wx, embed_gather, memset hA,
// memset vote} -- role selected by blockIdx. The embed-gather part keeps its
// exact original code and 10240-block geometry (latency-hiding unchanged);
// consolidation only removes 3 kernel-launch + 2 memset enqueue overheads.
//   blocks [0, 10240)      : embed gather (2 chains/thread)
//   blocks [10240, 10752)  : convert Wh -> frag-major f16
//   blocks [10752, 10816)  : convert Wx -> frag-major f16
//   blocks [10816, 11072)  : zero hA (8 MB)
//   block  11072           : zero vote/barrier region (8 KB)
// ---------------------------------------------------------------------------
__global__ __launch_bounds__(256) void prep(
        const int* __restrict__ inputs, const float* __restrict__ emb,
        _Float16* __restrict__ xe,
        const float* __restrict__ Wh, _Float16* __restrict__ Wf,
        const float* __restrict__ Wx, _Float16* __restrict__ Wxf,
        _Float16* __restrict__ hA, unsigned* __restrict__ vote) {
    const int bid = blockIdx.x;
    const int tid = threadIdx.x;

    if (bid < 10240) {
        // ---- embed gather (verbatim) ----
        const int c = bid * 256 + tid;
        int cid[2] = { c, c + 2621440 };
        const float* src[2];
        int kb[2];
        #pragma unroll
        for (int u = 0; u < 2; ++u) {
            int lane = cid[u] & 63, kblk = (cid[u] >> 6) & 3;
            int mblk = (cid[u] >> 8) & 255, t = cid[u] >> 16;
            int m = mblk * 16 + (lane & 15);
            kb[u] = kblk * 32 + (lane >> 4) * 8;
            int tok = inputs[m * TSTEPS + t];
            src[u] = emb + (size_t)tok * EDIM;
        }
        #pragma unroll
        for (int u = 0; u < 2; ++u) {
            half8 v;
            #pragma unroll
            for (int e = 0; e < 8; ++e)
                v[e] = (kb[u] + e < EDIM) ? (_Float16)src[u][kb[u] + e]
                                          : (_Float16)0.0f;
            *((half8*)xe + cid[u]) = v;
        }
    } else if (bid < 10752) {
        // ---- convert Wh ----
        int cid = (bid - 10240) * 256 + tid;
        int lane = cid & 63, kblk = (cid >> 6) & 31, nblk = cid >> 11;
        int n = nblk * 16 + (lane & 15);
        int kb = kblk * 32 + (lane >> 4) * 8;
        half8 v;
        #pragma unroll
        for (int e = 0; e < 8; ++e) v[e] = (_Float16)Wh[(kb + e) * UDIM + n];
        *((half8*)Wf + cid) = v;
    } else if (bid < 10816) {
        // ---- convert Wx ----
        int cid = (bid - 10752) * 256 + tid;
        int lane = cid & 63, kblk = (cid >> 6) & 3, nblk = cid >> 8;
        int n = nblk * 16 + (lane & 15);
        int kb = kblk * 32 + (lane >> 4) * 8;
        half8 v;
        #pragma unroll
        for (int e = 0; e < 8; ++e)
            v[e] = (kb + e < EDIM) ? (_Float16)Wx[(kb + e) * UDIM + n]
                                   : (_Float16)0.0f;
        *((half8*)Wxf + cid) = v;
    } else if (bid < 11072) {
        // ---- zero hA: 8 MB = 524288 half8; 65536 threads x 8 ----
        const int idx = (bid - 10816) * 256 + tid;
        half8 z;
        #pragma unroll
        for (int e = 0; e < 8; ++e) z[e] = (_Float16)0.0f;
        #pragma unroll
        for (int e = 0; e < 8; ++e) *((half8*)hA + (size_t)idx * 8 + e) = z;
    } else {
        // ---- zero vote/barg/bar/fbar region: 2048 u32 ----
        #pragma unroll
        for (int e = 0; e < 8; ++e) vote[tid + 256 * e] = 0u;
    }
}

// Persistent kernel, 256 blocks x 512 threads (2 waves/SIMD; 157.7 KB LDS
// keeps 1 block/CU). Tile 256(M) x 64(N), waves split M only (32M x 64N).
// B pinned in LDS all 80 steps; B dist-2, A dist-4; rotated visit order +
// own-chunk registers. BYTE-IDENTICAL to the session-best R4 kernel (863 us).
// Ledger: R1 flags 1004 / R2 resident-B 895 / R3 deep-prefetch 940 /
// R5 j-split 1076 / R6 anti-phase 1177 all refuted; this schedule is a sharp
// local optimum -- do not perturb without counter evidence.
__global__ __launch_bounds__(512, 2) void rnn_persist(
        _Float16* __restrict__ hA, _Float16* __restrict__ hB,
        const _Float16* __restrict__ xe,
        const _Float16* __restrict__ Wf, const _Float16* __restrict__ Wxf,
        const float* __restrict__ bias,
        unsigned* vote, unsigned* barg, unsigned* bar, unsigned* fbar)
{
    __shared__ __align__(16) _Float16 smem[B_HALFS + 8 * 640];  // 157696 B
    __shared__ unsigned sFast;

    const int tid  = threadIdx.x;
    const int lane = tid & 63, wave = tid >> 6;
    const int bid  = blockIdx.x;
    const int mt = bid & 15, nt = bid >> 4;
    const int lrow = lane & 15, lq = lane >> 4;

    // ---- XCD-locality vote + one global barrier (atomics only) ----
    if (tid == 0) {
        unsigned xcd = ((unsigned)__builtin_amdgcn_s_getreg(HWREG_XCC_ID)) & 7u;
        __hip_atomic_fetch_or(&vote[mt], 1u << xcd, __ATOMIC_RELAXED,
                              __HIP_MEMORY_SCOPE_AGENT);
        __builtin_amdgcn_s_waitcnt(0);
        __hip_atomic_fetch_add(barg, 1u, __ATOMIC_RELAXED, __HIP_MEMORY_SCOPE_AGENT);
        while (__hip_atomic_load(barg, __ATOMIC_RELAXED,
                                 __HIP_MEMORY_SCOPE_AGENT) < 256u)
            __builtin_amdgcn_s_sleep(1);
        unsigned allv = 0u, own = 0u;
        for (int g = 0; g < 16; ++g) {
            unsigned v = __hip_atomic_load(&vote[g], __ATOMIC_RELAXED,
                                           __HIP_MEMORY_SCOPE_AGENT);
            allv |= v;
            if (g == mt) own = v;
        }
        const bool single = own != 0u && (own & (own - 1u)) == 0u;
        sFast = (single && __popc(allv) == 8) ? 1u : 0u;
    }
    __syncthreads();
    const bool fast = sFast != 0u;

    // ---- Load B slice into LDS once: [j(4)][s(36)][lane][8]; waves 0-3 ----
    if (wave < 4) {
        const half8* wx8 = (const half8*)Wxf;
        const half8* wh8 = (const half8*)Wf;
        #pragma unroll 1
        for (int s = 0; s < 36; ++s) {
            const half8* src = (s < 4)
                ? wx8 + ((size_t)(nt * 4 + wave) * 4 + s) * 64 + lane
                : wh8 + ((size_t)(nt * 4 + wave) * 32 + (s - 4)) * 64 + lane;
            load_lds16(src, smem + ((wave * 36 + s) * 64 + lane) * 8);
        }
    }
    __syncthreads();

    _Float16* tb = smem + B_HALFS + wave * 640;   // epilogue scratch, wave-private

    float bj[4];
    #pragma unroll
    for (int j = 0; j < 4; ++j) bj[j] = bias[nt * 64 + j * 16 + lrow];

    int mblk[2];                                  // wave tile: 32 M rows
    #pragma unroll
    for (int i = 0; i < 2; ++i) mblk[i] = mt * 16 + wave * 2 + i;

    unsigned* mybar = bar + mt * 32;              // fallback single counter
    unsigned* mycnt = fbar + (mt * 16 + nt) * 4;  // own producer counter (16 B stride)

    const int cb = nt * 2;                        // rotated chunk base

#define LDB(bf, s) { _Pragma("unroll") \
    for (int j = 0; j < 4; ++j) \
        bf[j] = *(const half8*)&smem[(((j) * 36 + (s)) * 64 + lane) * 8]; }
#define LDBR(bf, v) { const int s_ = 4 + ((cb + (v)) & 31); _Pragma("unroll") \
    for (int j = 0; j < 4; ++j) \
        bf[j] = *(const half8*)&smem[((j * 36 + s_) * 64 + lane) * 8]; }
#define FMAB(A, B) { _Pragma("unroll") \
    for (int i = 0; i < 2; ++i) { _Pragma("unroll") \
        for (int j = 0; j < 4; ++j) \
            acc[i][j] = __builtin_amdgcn_mfma_f32_16x16x32_f16(A[i], B[j], acc[i][j], 0, 0, 0); } }
#define LDHR(A, v) { const int c_ = (cb + (v)) & 31; _Pragma("unroll") \
    for (int i = 0; i < 2; ++i) A[i] = pah[i][c_ * 64]; }
#define ZACC { _Pragma("unroll") \
    for (int i = 0; i < 2; ++i) { _Pragma("unroll") \
        for (int j = 0; j < 4; ++j) { acc[i][j][0]=0.f; acc[i][j][1]=0.f; acc[i][j][2]=0.f; acc[i][j][3]=0.f; } } }

    float4v acc[2][4];
    half8 a0[2], a1[2], a2[2], a3[2], b0[4], b1[4];
    half8 own0[2], own1[2];                       // own chunks (visits 0,1); h(0)=0
    #pragma unroll
    for (int e = 0; e < 8; ++e) {
        own0[0][e] = (_Float16)0.0f; own0[1][e] = (_Float16)0.0f;
        own1[0][e] = (_Float16)0.0f; own1[1][e] = (_Float16)0.0f;
    }

    // x-segment for a step: acc += xe_tn @ Wx  (B slices 0..3)
    auto xfma = [&](int tn) {
        const half8* xe8 = (const half8*)xe + (size_t)tn * 65536;
        #pragma unroll
        for (int i = 0; i < 2; ++i) {
            const half8* px = xe8 + (size_t)mblk[i] * 4 * 64 + lane;
            a0[i] = px[0]; a1[i] = px[64]; a2[i] = px[128]; a3[i] = px[192];
        }
        LDB(b0, 0); LDB(b1, 1);
        FMAB(a0, b0); LDB(b0, 2);
        FMAB(a1, b1); LDB(b1, 3);
        FMAB(a2, b0);
        FMAB(a3, b1);
    };

    ZACC;
    xfma(0);

    #pragma unroll 1
    for (int t = 0; t < TSTEPS; ++t) {
        const _Float16* hi = (t & 1) ? hB : hA;
        _Float16*       ho = (t & 1) ? hA : hB;

        const half8* pah[2];
        #pragma unroll
        for (int i = 0; i < 2; ++i)
            pah[i] = (const half8*)hi + (size_t)mblk[i] * 32 * 64 + lane;

        // ---- h-loop: 32 visits, rotated order chunk=(2nt+v)&31.
        //      Visits 0,1 = own chunks from registers (no load, no latency).
        //      A dist-4 (a2,a3 then loop-carried), B dist-2 (r0 schedule).
        #pragma unroll
        for (int i = 0; i < 2; ++i) { a0[i] = own0[i]; a1[i] = own1[i]; }
        LDHR(a2, 2); LDHR(a3, 3);
        LDBR(b0, 0); LDBR(b1, 1);
        #pragma unroll 1
        for (int v = 0; v < 28; v += 4) {
            FMAB(a0, b0); LDBR(b0, v + 2); LDHR(a0, v + 4);
            FMAB(a1, b1); LDBR(b1, v + 3); LDHR(a1, v + 5);
            FMAB(a2, b0); LDBR(b0, v + 4); LDHR(a2, v + 6);
            FMAB(a3, b1); LDBR(b1, v + 5); LDHR(a3, v + 7);
        }
        // tail: visits 28..31
        FMAB(a0, b0); LDBR(b0, 30);
        FMAB(a1, b1); LDBR(b1, 31);
        FMAB(a2, b0);
        FMAB(a3, b1);

        // ---- Epilogue: tanh + C-layout -> A-layout (wave-private LDS) ----
        #pragma unroll
        for (int i = 0; i < 2; ++i) {
            #pragma unroll
            for (int jp = 0; jp < 2; ++jp) {
                #pragma unroll
                for (int jj = 0; jj < 2; ++jj) {
                    const int j = jp * 2 + jj;
                    #pragma unroll
                    for (int r = 0; r < 4; ++r)
                        tb[(lq * 4 + r) * 40 + jj * 16 + lrow] =
                            (_Float16)tanh_fast(acc[i][j][r] + bj[j]);
                }
                // same-wave LDS RAW -> lgkmcnt only, no barrier
                half8 v = *(const half8*)&tb[lrow * 40 + lq * 8];
                if (jp == 0) own0[i] = v; else own1[i] = v;   // keep own chunks
                *((half8*)ho + (size_t)(mblk[i] * 32 + nt * 2 + jp) * 64 + lane) = v;
            }
        }

        // ---- x-segment of step t+1 (independent of h_{t+1}) BEFORE barrier ----
        if (t < TSTEPS - 1) {
            ZACC;
            xfma(t + 1);
            __syncthreads();    // drains all waves' h stores to L2
            if (fast) {
                // distributed barrier: parallel RMWs + 16-lane parallel spin
                if (tid == 0)
                    __hip_atomic_fetch_add(mycnt, 1u, __ATOMIC_RELAXED,
                                           __HIP_MEMORY_SCOPE_AGENT);
                if (tid < 16) {
                    while (__hip_atomic_load(&fbar[(mt * 16 + tid) * 4],
                                             __ATOMIC_RELAXED,
                                             __HIP_MEMORY_SCOPE_AGENT)
                           < (unsigned)(t + 1))
                        __builtin_amdgcn_s_sleep(1);
                }
            } else if (tid == 0) {
                __builtin_amdgcn_fence(__ATOMIC_RELEASE, "agent");
                __hip_atomic_fetch_add(mybar, 1u, __ATOMIC_RELAXED,
                                       __HIP_MEMORY_SCOPE_AGENT);
                const unsigned target = 16u * (unsigned)(t + 1);
                while (__hip_atomic_load(mybar, __ATOMIC_RELAXED,
                                         __HIP_MEMORY_SCOPE_AGENT) < target)
                    __builtin_amdgcn_s_sleep(1);
                __builtin_amdgcn_fence(__ATOMIC_ACQUIRE, "agent");
            }
            __syncthreads();
        }
    }
#undef LDB
#undef LDBR
#undef FMAB
#undef LDHR
#undef ZACC
}

// out[b] = h[b,:].Wo + bo, h frag-major
__global__ __launch_bounds__(256) void out_proj(const _Float16* __restrict__ h,
                                                const float* __restrict__ Wo,
                                                const float* __restrict__ bo,
                                                float* __restrict__ out) {
    const int lane = threadIdx.x & 63;
    const int wave = threadIdx.x >> 6;
    const int row = blockIdx.x * 4 + wave;
    const int mblk = row >> 4, lb = row & 15;
    const half8* hf = (const half8*)h;
    float s = 0.0f;
    #pragma unroll
    for (int c = 0; c < 2; ++c) {
        const int kblk = lane >> 1;
        const int q = (lane & 1) * 2 + c;
        half8 v = hf[(size_t)(mblk * 32 + kblk) * 64 + lb + q * 16];
        const int k0 = kblk * 32 + q * 8;
        #pragma unroll
        for (int e = 0; e < 8; ++e) s += (float)v[e] * Wo[k0 + e];
    }
    #pragma unroll
    for (int off = 32; off > 0; off >>= 1) s += __shfl_down(s, off, 64);
    if (lane == 0) out[row] = s + bo[0];
}

extern "C" void kernel_launch(void* const* d_in, const int* in_sizes, int n_in,
                              void* d_out, int out_size, void* d_ws, size_t ws_size,
                              hipStream_t stream) {
    const int*   inputs = (const int*)  d_in[0];
    const float* emb    = (const float*)d_in[1];
    const float* Wx     = (const float*)d_in[2];
    const float* Wh     = (const float*)d_in[3];
    const float* b      = (const float*)d_in[4];
    const float* Wo     = (const float*)d_in[5];
    const float* bo     = (const float*)d_in[6];
    float* out = (float*)d_out;

    char* ws = (char*)d_ws;
    _Float16* Wf   = (_Float16*)ws;                          // 2 MB
    _Float16* Wxf  = (_Float16*)(ws + (2u  << 20));          // 256 KB
    _Float16* hA   = (_Float16*)(ws + (3u  << 20));          // 8 MB
    _Float16* hB   = (_Float16*)(ws + (11u << 20));          // 8 MB
    _Float16* xe   = (_Float16*)(ws + (19u << 20));          // 84 MB
    unsigned* vote = (unsigned*)(ws + (103u << 20));         // 16 u32
    unsigned* barg = vote + 16;                              // 1 u32
    unsigned* bar  = vote + 256;                             // 16 x 32-u32 (fallback)
    unsigned* fbar = vote + 1024;                            // 16 x 16 x 4-u32 (fast)

    // One prep kernel: embed gather + both weight converts + hA zero + vote
    // zero (8 KB covering vote/barg/bar/fbar). 3 enqueues total vs 6.
    prep<<<dim3(11073), dim3(256), 0, stream>>>(inputs, emb, xe, Wh, Wf,
                                                Wx, Wxf, hA, vote);

    rnn_persist<<<dim3(256), dim3(512), 0, stream>>>(hA, hB, xe, Wf, Wxf, b,
                                                     vote, barg, bar, fbar);

    // T=80 even -> final h in hA
    out_proj<<<dim3(1024), dim3(256), 0, stream>>>(hA, Wo, bo, out);
}